// Round 5
// baseline (20878.879 us; speedup 1.0000x reference)
//
#include <hip/hip_runtime.h>

typedef __attribute__((ext_vector_type(8))) short short8;
typedef __attribute__((ext_vector_type(4))) float f32x4;
typedef unsigned long long ull;

#define DT (1.0f/256.0f)
#define NSTEPS 256

__device__ __forceinline__ short f2bf(float f) {
    unsigned u = __float_as_uint(f);
    u = (u + 0x7fffu + ((u >> 16) & 1u)) >> 16;
    return (short)u;
}
__device__ __forceinline__ float fast_tanh(float x) {
    float e = __expf(2.f * x);
    return 1.f - __fdividef(2.f, e + 1.f);
}

// RELAXED agent-scope ops: visible at the coherence point, NO cache-invalidate
// instructions (round-3 lesson: acquire/release at agent scope nukes L2 chip-wide).
__device__ __forceinline__ void st_agent_f(float* p, float v) {
    __hip_atomic_store(p, v, __ATOMIC_RELAXED, __HIP_MEMORY_SCOPE_AGENT);
}
__device__ __forceinline__ void st_agent_u32(unsigned* p, unsigned v) {
    __hip_atomic_store(p, v, __ATOMIC_RELAXED, __HIP_MEMORY_SCOPE_AGENT);
}
__device__ __forceinline__ ull ld_agent_u64(const void* p) {
    return __hip_atomic_load((const ull*)p, __ATOMIC_RELAXED, __HIP_MEMORY_SCOPE_AGENT);
}

// ---------------- weight permutation (A-fragment order, bf16) ----------------
// A-frag for mfma_f32_16x16x32_bf16: lane l holds A[m = l&15][k = kc*32 + (l>>4)*8 + j]
__global__ void perm_w0(const float* __restrict__ W0, short* __restrict__ W0p) {
    int i = blockIdx.x * 256 + threadIdx.x;            // 32768 = 16ot*4kc*64*8
    int j = i & 7, l = (i >> 3) & 63, kc = (i >> 9) & 3, ot = i >> 11;
    int row = ot * 16 + (l & 15);
    int col = kc * 32 + ((l >> 4) << 3) + j;
    W0p[i] = f2bf(W0[row * 128 + col]);
}
__global__ void perm_w1(const float* __restrict__ W1, short* __restrict__ W1p) {
    int i = blockIdx.x * 256 + threadIdx.x;            // 65536 = 16ot*8kc*64*8
    int j = i & 7, l = (i >> 3) & 63, kc = (i >> 9) & 7, ot = i >> 12;
    int row = ot * 16 + (l & 15);
    int col = kc * 32 + ((l >> 4) << 3) + j;
    W1p[i] = f2bf(W1[row * 256 + col]);
}
// A-tile = 16 rows = (lv_in 0..3)*4 + hl : W2 row (ht*4+hl)*63 + q4*4+lv_in ; lv>=63 zero pad
__global__ void perm_w2(const float* __restrict__ W2, short* __restrict__ W2p) {
    int i = blockIdx.x * 256 + threadIdx.x;            // 2097152 = 32ht*16q4*8kc*64*8
    int j = i & 7, ln = (i >> 3) & 63, kc = (i >> 9) & 7;
    int q4 = (i >> 12) & 15, ht = i >> 16;
    int m = ln & 15;
    int hl = m & 3, lvin = m >> 2;
    int lv = q4 * 4 + lvin;
    if (lv >= 63) { W2p[i] = 0; return; }
    int row = (ht * 4 + hl) * 63 + lv;
    int col = kc * 32 + ((ln >> 4) << 3) + j;
    W2p[i] = f2bf(W2[row * 256 + col]);
}

// ---------------- y0 = x0 @ l1w^T + l1b (f32 state + bf16 exchange slot 0) ----------------
__global__ void y0_kernel(const float* __restrict__ x0, const float* __restrict__ l1w,
                          const float* __restrict__ l1b, float* __restrict__ y0f,
                          unsigned short* __restrict__ ybf) {
    int i = blockIdx.x * 256 + threadIdx.x;            // 65536
    int b = i >> 7, h = i & 127;
    float s = l1b[h];
    #pragma unroll
    for (int d = 0; d < 8; ++d) s += x0[b * 8 + d] * l1w[h * 8 + d];
    y0f[i] = s;
    ybf[i] = (unsigned short)f2bf(s);
}

// ---------------- persistent RK integrator ----------------
// grid 256 = 8 bg (64 batch rows) x 32 ht (4 h each); 512 threads (8 waves); 1 WG/CU
struct Smem {
    alignas(16) short ysb[64 * 136];    // [b][h] stage input, bf16
    alignas(16) short h1b[64 * 264];    // [b][ho]
    alignas(16) short h2b[64 * 264];
    float gsh[64 * 65];                 // [b][lv] (lv=63 zero pad)
    float b2sh[4 * 64];                 // [hl][lv]
    float b0sh[256];
    float b1sh[256];
    float kred[8][4][4][17];            // [wave][bq][hl][b16]
};

__constant__ const float cA2[1] = {0.161f};
__constant__ const float cA3[2] = {-0.008480655492356989f, 0.335480655492357f};
__constant__ const float cA4[3] = {2.8971530571054935f, -6.359448489975075f, 4.3622954328695815f};
__constant__ const float cA5[4] = {5.325864828439257f, -11.748883564062828f, 7.4955393428898365f, -0.09249506636175525f};
__constant__ const float cA6[5] = {5.86145544294642f, -12.92096931784711f, 8.159367898576159f, -0.071584973281401f, -0.028269050394068383f};

template<int STAGE>
__device__ __forceinline__ void do_stage(
    Smem& sm, int s, int gsi, int bg, int ht, int tid,
    unsigned short* __restrict__ ybf,     // 2 x 65536 bf16 (double buffer)
    float* __restrict__ yfinal,
    const short* __restrict__ W0p, const short* __restrict__ W1p, const short* __restrict__ W2p,
    const float* __restrict__ logsig,
    unsigned* __restrict__ barctr,
    float (&yreg)[2], float (&kr)[2][5])
{
    const int w    = tid >> 6;
    const int lane = tid & 63;
    const int q    = lane >> 4;
    const int rr   = lane & 15;
    const unsigned short* ycur = ybf + (gsi & 1) * 65536;
    unsigned short*       ynxt = ybf + ((gsi + 1) & 1) * 65536;

    // ---- pre-barrier independent work: g refresh (idx=s) at stage 2 ----
    if constexpr (STAGE == 2) {
        const int b = tid >> 3, l0 = (tid & 7) * 8;
        const float* gp = logsig + (bg * 64 + b) * 16384 + s * 64 + 1;
        #pragma unroll
        for (int ii = 0; ii < 8; ++ii) {
            int l = l0 + ii;
            sm.gsh[b * 65 + l] = (l < 63) ? gp[l] : 0.f;
        }
    }

    // ---- wait: all 32 ht-WGs of this bg flagged stage gsi-1 complete ----
    if (gsi > 0 && tid == 0) {
        const unsigned target = 32u * (unsigned)gsi;
        while (__hip_atomic_load(&barctr[bg * 16], __ATOMIC_RELAXED, __HIP_MEMORY_SCOPE_AGENT) < target) { }
    }
    __syncthreads();

    // ---------- phase 0: uncached bf16 y -> ysb ----------
    {
        const int b = tid >> 3, h0 = (tid & 7) * 16;
        const ull* src = (const ull*)(ycur + (bg * 64 + b) * 128 + h0);
        ull v0 = ld_agent_u64(src + 0);
        ull v1 = ld_agent_u64(src + 1);
        ull v2 = ld_agent_u64(src + 2);
        ull v3 = ld_agent_u64(src + 3);
        ull* dst = (ull*)&sm.ysb[b * 136 + h0];
        dst[0] = v0; dst[1] = v1; dst[2] = v2; dst[3] = v3;
    }
    __syncthreads();

    // ---------- phase 1: h1 = silu(W0 @ ys^T + b0), wave w -> ot {2w,2w+1} x 4 bq ----------
    {
        f32x4 acc[2][4];
        #pragma unroll
        for (int oi = 0; oi < 2; ++oi)
            #pragma unroll
            for (int bq = 0; bq < 4; ++bq) acc[oi][bq] = (f32x4){0.f, 0.f, 0.f, 0.f};
        #pragma unroll
        for (int kc = 0; kc < 4; ++kc) {
            short8 bfr[4];
            #pragma unroll
            for (int bq = 0; bq < 4; ++bq)
                bfr[bq] = *reinterpret_cast<const short8*>(&sm.ysb[(bq * 16 + rr) * 136 + kc * 32 + q * 8]);
            #pragma unroll
            for (int oi = 0; oi < 2; ++oi) {
                short8 af = *reinterpret_cast<const short8*>(W0p + ((w * 2 + oi) * 4 + kc) * 512 + lane * 8);
                #pragma unroll
                for (int bq = 0; bq < 4; ++bq)
                    acc[oi][bq] = __builtin_amdgcn_mfma_f32_16x16x32_bf16(af, bfr[bq], acc[oi][bq], 0, 0, 0);
            }
        }
        #pragma unroll
        for (int oi = 0; oi < 2; ++oi) {
            const int ho = (w * 2 + oi) * 16 + q * 4;
            #pragma unroll
            for (int bq = 0; bq < 4; ++bq) {
                float vv[4];
                #pragma unroll
                for (int j = 0; j < 4; ++j) {
                    float x = acc[oi][bq][j] + sm.b0sh[ho + j];
                    vv[j] = x * __fdividef(1.f, 1.f + __expf(-x));
                }
                unsigned lo = (unsigned)(unsigned short)f2bf(vv[0]) | ((unsigned)(unsigned short)f2bf(vv[1]) << 16);
                unsigned hi = (unsigned)(unsigned short)f2bf(vv[2]) | ((unsigned)(unsigned short)f2bf(vv[3]) << 16);
                unsigned* d = reinterpret_cast<unsigned*>(&sm.h1b[(bq * 16 + rr) * 264 + ho]);
                d[0] = lo; d[1] = hi;
            }
        }
    }
    __syncthreads();

    // ---------- phase 2: h2 = silu(W1 @ h1^T + b1) ----------
    {
        f32x4 acc[2][4];
        #pragma unroll
        for (int oi = 0; oi < 2; ++oi)
            #pragma unroll
            for (int bq = 0; bq < 4; ++bq) acc[oi][bq] = (f32x4){0.f, 0.f, 0.f, 0.f};
        #pragma unroll
        for (int kc = 0; kc < 8; ++kc) {
            short8 bfr[4];
            #pragma unroll
            for (int bq = 0; bq < 4; ++bq)
                bfr[bq] = *reinterpret_cast<const short8*>(&sm.h1b[(bq * 16 + rr) * 264 + kc * 32 + q * 8]);
            #pragma unroll
            for (int oi = 0; oi < 2; ++oi) {
                short8 af = *reinterpret_cast<const short8*>(W1p + ((w * 2 + oi) * 8 + kc) * 512 + lane * 8);
                #pragma unroll
                for (int bq = 0; bq < 4; ++bq)
                    acc[oi][bq] = __builtin_amdgcn_mfma_f32_16x16x32_bf16(af, bfr[bq], acc[oi][bq], 0, 0, 0);
            }
        }
        #pragma unroll
        for (int oi = 0; oi < 2; ++oi) {
            const int ho = (w * 2 + oi) * 16 + q * 4;
            #pragma unroll
            for (int bq = 0; bq < 4; ++bq) {
                float vv[4];
                #pragma unroll
                for (int j = 0; j < 4; ++j) {
                    float x = acc[oi][bq][j] + sm.b1sh[ho + j];
                    vv[j] = x * __fdividef(1.f, 1.f + __expf(-x));
                }
                unsigned lo = (unsigned)(unsigned short)f2bf(vv[0]) | ((unsigned)(unsigned short)f2bf(vv[1]) << 16);
                unsigned hi = (unsigned)(unsigned short)f2bf(vv[2]) | ((unsigned)(unsigned short)f2bf(vv[3]) << 16);
                unsigned* d = reinterpret_cast<unsigned*>(&sm.h2b[(bq * 16 + rr) * 264 + ho]);
                d[0] = lo; d[1] = hi;
            }
        }
    }
    __syncthreads();

    // ---------- phase 3: A-tile = 4h x 4lv of W2; wave w -> q4 {2w,2w+1} x 4 bq ----------
    {
        f32x4 acc[2][4];
        #pragma unroll
        for (int t2 = 0; t2 < 2; ++t2)
            #pragma unroll
            for (int bq = 0; bq < 4; ++bq) acc[t2][bq] = (f32x4){0.f, 0.f, 0.f, 0.f};
        #pragma unroll
        for (int kc = 0; kc < 8; ++kc) {
            short8 bfr[4];
            #pragma unroll
            for (int bq = 0; bq < 4; ++bq)
                bfr[bq] = *reinterpret_cast<const short8*>(&sm.h2b[(bq * 16 + rr) * 264 + kc * 32 + q * 8]);
            #pragma unroll
            for (int t2 = 0; t2 < 2; ++t2) {
                short8 af = *reinterpret_cast<const short8*>(W2p + (size_t)(ht * 16 + w * 2 + t2) * 4096 + kc * 512 + lane * 8);
                #pragma unroll
                for (int bq = 0; bq < 4; ++bq)
                    acc[t2][bq] = __builtin_amdgcn_mfma_f32_16x16x32_bf16(af, bfr[bq], acc[t2][bq], 0, 0, 0);
            }
        }
        // per lane: batch col = bq*16 + rr, lv = q4*4 + q, h_local = j
        float kacc[4][4];
        #pragma unroll
        for (int bq = 0; bq < 4; ++bq)
            #pragma unroll
            for (int j = 0; j < 4; ++j) kacc[bq][j] = 0.f;
        #pragma unroll
        for (int t2 = 0; t2 < 2; ++t2) {
            const int lv = (w * 2 + t2) * 4 + q;
            #pragma unroll
            for (int bq = 0; bq < 4; ++bq) {
                float gv = sm.gsh[(bq * 16 + rr) * 65 + lv];
                #pragma unroll
                for (int j = 0; j < 4; ++j) {
                    float x = acc[t2][bq][j] + sm.b2sh[j * 64 + lv];
                    kacc[bq][j] += fast_tanh(x) * gv;
                }
            }
        }
        // reduce over lv-quarter groups (lane bits 4,5)
        #pragma unroll
        for (int bq = 0; bq < 4; ++bq)
            #pragma unroll
            for (int j = 0; j < 4; ++j) {
                float v = kacc[bq][j];
                v += __shfl_xor(v, 16);
                v += __shfl_xor(v, 32);
                kacc[bq][j] = v;
            }
        if (q == 0) {
            #pragma unroll
            for (int bq = 0; bq < 4; ++bq)
                #pragma unroll
                for (int j = 0; j < 4; ++j)
                    sm.kred[w][bq][j][rr] = kacc[bq][j];
        }
    }
    __syncthreads();

    // ---------- epilogue: 128 owner threads, each (b, 2 h) ----------
    if (tid < 128) {
        const int b = tid >> 1, hs = tid & 1;
        float s0 = 0.f, s1 = 0.f;
        #pragma unroll
        for (int ww = 0; ww < 8; ++ww) {
            s0 += sm.kred[ww][b >> 4][hs * 2 + 0][b & 15];
            s1 += sm.kred[ww][b >> 4][hs * 2 + 1][b & 15];
        }
        float nv0, nv1;
        if constexpr (STAGE == 1) {
            kr[0][0] = s0; kr[1][0] = s1;
            nv0 = yreg[0] + DT * (cA2[0] * s0);
            nv1 = yreg[1] + DT * (cA2[0] * s1);
        } else if constexpr (STAGE == 2) {
            kr[0][1] = s0; kr[1][1] = s1;
            nv0 = yreg[0] + DT * (cA3[0] * kr[0][0] + cA3[1] * s0);
            nv1 = yreg[1] + DT * (cA3[0] * kr[1][0] + cA3[1] * s1);
        } else if constexpr (STAGE == 3) {
            kr[0][2] = s0; kr[1][2] = s1;
            nv0 = yreg[0] + DT * (cA4[0] * kr[0][0] + cA4[1] * kr[0][1] + cA4[2] * s0);
            nv1 = yreg[1] + DT * (cA4[0] * kr[1][0] + cA4[1] * kr[1][1] + cA4[2] * s1);
        } else if constexpr (STAGE == 4) {
            kr[0][3] = s0; kr[1][3] = s1;
            nv0 = yreg[0] + DT * (cA5[0] * kr[0][0] + cA5[1] * kr[0][1] + cA5[2] * kr[0][2] + cA5[3] * s0);
            nv1 = yreg[1] + DT * (cA5[0] * kr[1][0] + cA5[1] * kr[1][1] + cA5[2] * kr[1][2] + cA5[3] * s1);
        } else if constexpr (STAGE == 5) {
            kr[0][4] = s0; kr[1][4] = s1;
            nv0 = yreg[0] + DT * (cA6[0] * kr[0][0] + cA6[1] * kr[0][1] + cA6[2] * kr[0][2] + cA6[3] * kr[0][3] + cA6[4] * s0);
            nv1 = yreg[1] + DT * (cA6[0] * kr[1][0] + cA6[1] * kr[1][1] + cA6[2] * kr[1][2] + cA6[3] * kr[1][3] + cA6[4] * s1);
        } else {
            nv0 = yreg[0] + DT * (0.09646076681806523f * kr[0][0] + 0.01f * kr[0][1]
                 + 0.4798896504144996f * kr[0][2] + 1.379008574103742f * kr[0][3]
                 + (-3.290069515436081f) * kr[0][4] + 2.324710524099774f * s0);
            nv1 = yreg[1] + DT * (0.09646076681806523f * kr[1][0] + 0.01f * kr[1][1]
                 + 0.4798896504144996f * kr[1][2] + 1.379008574103742f * kr[1][3]
                 + (-3.290069515436081f) * kr[1][4] + 2.324710524099774f * s1);
            yreg[0] = nv0; yreg[1] = nv1;
        }
        const int gi = (bg * 64 + b) * 128 + ht * 4 + hs * 2;
        unsigned pk = (unsigned)(unsigned short)f2bf(nv0) | ((unsigned)(unsigned short)f2bf(nv1) << 16);
        st_agent_u32(reinterpret_cast<unsigned*>(ynxt + gi), pk);
        if constexpr (STAGE == 6) {
            if (s == NSTEPS - 1) {
                st_agent_f(&yfinal[gi], nv0);
                st_agent_f(&yfinal[gi + 1], nv1);
            }
        }
    }

    // ---------- flag (syncthreads drains vmcnt -> stores visible before add) ----------
    __syncthreads();
    if (tid == 0)
        __hip_atomic_fetch_add(&barctr[bg * 16], 1u, __ATOMIC_RELAXED, __HIP_MEMORY_SCOPE_AGENT);
}

__global__ __launch_bounds__(512, 2) void rde_persistent(
    float* y0f, unsigned short* ybf, float* yfinal, unsigned* barctr,
    const short* W0p, const short* W1p, const short* W2p,
    const float* b0, const float* b1, const float* b2,
    const float* logsig)
{
    __shared__ Smem sm;
    const int tid = threadIdx.x;
    const int bg  = blockIdx.x >> 5;    // 0..7  (64 batch rows)
    const int ht  = blockIdx.x & 31;    // 0..31 (4 h) ; ht&7 == XCD
    // ---- one-time LDS init ----
    if (tid < 256) {
        sm.b0sh[tid] = b0[tid];
        int hl = tid >> 6, lv = tid & 63;
        sm.b2sh[tid] = (lv < 63) ? b2[(ht * 4 + hl) * 63 + lv] : 0.f;
    } else {
        sm.b1sh[tid - 256] = b1[tid - 256];
    }
    {
        const int b = tid >> 3, l0 = (tid & 7) * 8;
        const float* gp = logsig + (bg * 64 + b) * 16384 + 1;   // idx 0
        #pragma unroll
        for (int ii = 0; ii < 8; ++ii) {
            int l = l0 + ii;
            sm.gsh[b * 65 + l] = (l < 63) ? gp[l] : 0.f;
        }
    }
    float yreg[2] = {0.f, 0.f};
    float kr[2][5] = {{0.f,0.f,0.f,0.f,0.f},{0.f,0.f,0.f,0.f,0.f}};
    if (tid < 128) {
        const int b = tid >> 1, hs = tid & 1;
        const int gi = (bg * 64 + b) * 128 + ht * 4 + hs * 2;
        yreg[0] = y0f[gi];
        yreg[1] = y0f[gi + 1];
    }
    // (first syncthreads inside do_stage<1> covers init)
    #pragma unroll 1
    for (int s = 0; s < NSTEPS; ++s) {
        const int g6 = s * 6;
        do_stage<1>(sm, s, g6 + 0, bg, ht, tid, ybf, yfinal, W0p, W1p, W2p, logsig, barctr, yreg, kr);
        do_stage<2>(sm, s, g6 + 1, bg, ht, tid, ybf, yfinal, W0p, W1p, W2p, logsig, barctr, yreg, kr);
        do_stage<3>(sm, s, g6 + 2, bg, ht, tid, ybf, yfinal, W0p, W1p, W2p, logsig, barctr, yreg, kr);
        do_stage<4>(sm, s, g6 + 3, bg, ht, tid, ybf, yfinal, W0p, W1p, W2p, logsig, barctr, yreg, kr);
        do_stage<5>(sm, s, g6 + 4, bg, ht, tid, ybf, yfinal, W0p, W1p, W2p, logsig, barctr, yreg, kr);
        do_stage<6>(sm, s, g6 + 5, bg, ht, tid, ybf, yfinal, W0p, W1p, W2p, logsig, barctr, yreg, kr);
    }
}

// ---------------- final: softmax(yf @ l2w^T + l2b) ----------------
__global__ void out_kernel(const float* __restrict__ yf, const float* __restrict__ l2w,
                           const float* __restrict__ l2b, float* __restrict__ out) {
    int b = blockIdx.x, t = threadIdx.x;   // 64 threads
    float ya = yf[b * 128 + t], yb = yf[b * 128 + 64 + t];
    __shared__ float lg[10];
    for (int c = 0; c < 10; ++c) {
        float p = ya * l2w[c * 128 + t] + yb * l2w[c * 128 + 64 + t];
        for (int off = 32; off > 0; off >>= 1) p += __shfl_down(p, off);
        if (t == 0) lg[c] = p + l2b[c];
    }
    __syncthreads();
    if (t == 0) {
        float m = lg[0];
        for (int c = 1; c < 10; ++c) m = fmaxf(m, lg[c]);
        float s = 0.f, e[10];
        for (int c = 0; c < 10; ++c) { e[c] = expf(lg[c] - m); s += e[c]; }
        for (int c = 0; c < 10; ++c) out[b * 10 + c] = e[c] / s;
    }
}

extern "C" void kernel_launch(void* const* d_in, const int* in_sizes, int n_in,
                              void* d_out, int out_size, void* d_ws, size_t ws_size,
                              hipStream_t stream) {
    const float* logsig = (const float*)d_in[2];
    const float* x0  = (const float*)d_in[3];
    const float* W0  = (const float*)d_in[4];
    const float* b0  = (const float*)d_in[5];
    const float* W1  = (const float*)d_in[6];
    const float* b1  = (const float*)d_in[7];
    const float* W2  = (const float*)d_in[8];
    const float* b2  = (const float*)d_in[9];
    const float* l1w = (const float*)d_in[10];
    const float* l1b = (const float*)d_in[11];
    const float* l2w = (const float*)d_in[12];
    const float* l2b = (const float*)d_in[13];
    float* out = (float*)d_out;

    char* ws = (char*)d_ws;
    float*          y0f    = (float*)(ws);                  // 256 KB f32
    unsigned short* ybf    = (unsigned short*)(ws + 262144);// 2 x 128 KB bf16
    float*          yfinal = (float*)(ws + 524288);         // 256 KB f32
    short*          W0p    = (short*)(ws + 786432);         // 64 KB
    short*          W1p    = (short*)(ws + 851968);         // 128 KB
    short*          W2p    = (short*)(ws + 983040);         // 4 MB
    unsigned*       barctr = (unsigned*)(ws + 5177344);     // 8 bg x 16 uints

    hipMemsetAsync(barctr, 0, 32 * 16 * sizeof(unsigned), stream);
    perm_w0<<<128, 256, 0, stream>>>(W0, W0p);
    perm_w1<<<256, 256, 0, stream>>>(W1, W1p);
    perm_w2<<<8192, 256, 0, stream>>>(W2, W2p);
    y0_kernel<<<256, 256, 0, stream>>>(x0, l1w, l1b, y0f, ybf);

    void* args[] = {&y0f, &ybf, &yfinal, &barctr, &W0p, &W1p, &W2p, &b0, &b1, &b2, &logsig};
    hipLaunchCooperativeKernel((const void*)rde_persistent, dim3(256), dim3(512), args, 0, stream);

    out_kernel<<<512, 64, 0, stream>>>(yfinal, l2w, l2b, out);
}

// Round 6
// 15474.641 us; speedup vs baseline: 1.3492x; 1.3492x over previous
//
#include <hip/hip_runtime.h>

typedef __attribute__((ext_vector_type(8))) short short8;
typedef __attribute__((ext_vector_type(4))) float f32x4;
typedef unsigned long long ull;

#define DT (1.0f/256.0f)
#define NSTEPS 256

__device__ __forceinline__ short f2bf(float f) {
    unsigned u = __float_as_uint(f);
    u = (u + 0x7fffu + ((u >> 16) & 1u)) >> 16;
    return (short)u;
}
// packed f32x2 -> bf16x2 (RNE, single instruction)
__device__ __forceinline__ unsigned cvtpk(float a, float b) {
    unsigned r;
    asm("v_cvt_pk_bf16_f32 %0, %1, %2" : "=v"(r) : "v"(a), "v"(b));
    return r;
}
__device__ __forceinline__ float fast_silu(float x) {
    float e = __expf(-x);
    return x * __builtin_amdgcn_rcpf(1.f + e);
}
__device__ __forceinline__ float fast_tanh(float x) {
    float e = __expf(2.f * x);
    return 1.f - 2.f * __builtin_amdgcn_rcpf(e + 1.f);
}

// RELAXED agent-scope ops: visible at the coherence point, NO cache-invalidate
// instructions (round-3 lesson: acquire/release at agent scope nukes L2 chip-wide).
__device__ __forceinline__ void st_agent_f(float* p, float v) {
    __hip_atomic_store(p, v, __ATOMIC_RELAXED, __HIP_MEMORY_SCOPE_AGENT);
}
__device__ __forceinline__ void st_agent_u32(unsigned* p, unsigned v) {
    __hip_atomic_store(p, v, __ATOMIC_RELAXED, __HIP_MEMORY_SCOPE_AGENT);
}
__device__ __forceinline__ ull ld_agent_u64(const void* p) {
    return __hip_atomic_load((const ull*)p, __ATOMIC_RELAXED, __HIP_MEMORY_SCOPE_AGENT);
}

// ---------------- weight permutation (A-fragment order, bf16) ----------------
// A-frag for mfma_f32_16x16x32_bf16: lane l holds A[m = l&15][k = kc*32 + (l>>4)*8 + j]
__global__ void perm_w0(const float* __restrict__ W0, short* __restrict__ W0p) {
    int i = blockIdx.x * 256 + threadIdx.x;            // 32768 = 16ot*4kc*64*8
    int j = i & 7, l = (i >> 3) & 63, kc = (i >> 9) & 3, ot = i >> 11;
    int row = ot * 16 + (l & 15);
    int col = kc * 32 + ((l >> 4) << 3) + j;
    W0p[i] = f2bf(W0[row * 128 + col]);
}
__global__ void perm_w1(const float* __restrict__ W1, short* __restrict__ W1p) {
    int i = blockIdx.x * 256 + threadIdx.x;            // 65536 = 16ot*8kc*64*8
    int j = i & 7, l = (i >> 3) & 63, kc = (i >> 9) & 7, ot = i >> 12;
    int row = ot * 16 + (l & 15);
    int col = kc * 32 + ((l >> 4) << 3) + j;
    W1p[i] = f2bf(W1[row * 256 + col]);
}
// A-tile = 16 rows = (lv_in 0..3)*4 + hl : W2 row (ht*4+hl)*63 + q4*4+lv_in ; lv>=63 zero pad
__global__ void perm_w2(const float* __restrict__ W2, short* __restrict__ W2p) {
    int i = blockIdx.x * 256 + threadIdx.x;            // 2097152 = 32ht*16q4*8kc*64*8
    int j = i & 7, ln = (i >> 3) & 63, kc = (i >> 9) & 7;
    int q4 = (i >> 12) & 15, ht = i >> 16;
    int m = ln & 15;
    int hl = m & 3, lvin = m >> 2;
    int lv = q4 * 4 + lvin;
    if (lv >= 63) { W2p[i] = 0; return; }
    int row = (ht * 4 + hl) * 63 + lv;
    int col = kc * 32 + ((ln >> 4) << 3) + j;
    W2p[i] = f2bf(W2[row * 256 + col]);
}

// ---------------- y0 = x0 @ l1w^T + l1b (f32 state + bf16 exchange slot 0) ----------------
__global__ void y0_kernel(const float* __restrict__ x0, const float* __restrict__ l1w,
                          const float* __restrict__ l1b, float* __restrict__ y0f,
                          unsigned short* __restrict__ ybf) {
    int i = blockIdx.x * 256 + threadIdx.x;            // 65536
    int b = i >> 7, h = i & 127;
    float s = l1b[h];
    #pragma unroll
    for (int d = 0; d < 8; ++d) s += x0[b * 8 + d] * l1w[h * 8 + d];
    y0f[i] = s;
    ybf[i] = (unsigned short)f2bf(s);
}

// ---------------- persistent RK integrator ----------------
// grid 256 = 8 bg (64 batch rows) x 32 ht (4 h each); 512 threads (8 waves); 1 WG/CU
struct Smem {
    alignas(16) short ysb[64 * 136];    // [b][h] stage input, bf16
    alignas(16) short h1b[64 * 264];    // [b][ho]
    alignas(16) short h2b[64 * 264];
    float gsh[64 * 65];                 // [b][lv] (lv=63 zero pad)
    float b2sh[4 * 64];                 // [hl][lv]
    float b0sh[256];
    float b1sh[256];
    float kred[8][4][4][17];            // [wave][bq][hl][b16]
};

__constant__ const float cA2[1] = {0.161f};
__constant__ const float cA3[2] = {-0.008480655492356989f, 0.335480655492357f};
__constant__ const float cA4[3] = {2.8971530571054935f, -6.359448489975075f, 4.3622954328695815f};
__constant__ const float cA5[4] = {5.325864828439257f, -11.748883564062828f, 7.4955393428898365f, -0.09249506636175525f};
__constant__ const float cA6[5] = {5.86145544294642f, -12.92096931784711f, 8.159367898576159f, -0.071584973281401f, -0.028269050394068383f};

template<int STAGE>
__device__ __forceinline__ void do_stage(
    Smem& sm, int s, int gsi, int bg, int ht, int tid,
    unsigned short* __restrict__ ybf,     // 2 x 65536 bf16 (double buffer)
    float* __restrict__ yfinal,
    const short* __restrict__ W0p, const short* __restrict__ W1p, const short* __restrict__ W2p,
    const float* __restrict__ logsig,
    unsigned* __restrict__ barctr,
    float (&yreg)[2], float (&kr)[2][5])
{
    const int w    = tid >> 6;
    const int lane = tid & 63;
    const int q    = lane >> 4;
    const int rr   = lane & 15;
    const unsigned short* ycur = ybf + (gsi & 1) * 65536;
    unsigned short*       ynxt = ybf + ((gsi + 1) & 1) * 65536;

    // ---- pre-barrier independent work: g refresh (idx=s) at stage 2 ----
    if constexpr (STAGE == 2) {
        const int b = tid >> 3, l0 = (tid & 7) * 8;
        const float* gp = logsig + (bg * 64 + b) * 16384 + s * 64 + 1;
        #pragma unroll
        for (int ii = 0; ii < 8; ++ii) {
            int l = l0 + ii;
            sm.gsh[b * 65 + l] = (l < 63) ? gp[l] : 0.f;
        }
    }

    // ---- wait: all 32 ht-WGs of this bg flagged stage gsi-1 complete ----
    if (gsi > 0 && tid == 0) {
        const unsigned target = 32u * (unsigned)gsi;
        while (__hip_atomic_load(&barctr[bg * 16], __ATOMIC_RELAXED, __HIP_MEMORY_SCOPE_AGENT) < target) { }
    }
    __syncthreads();

    // ---------- phase 0: uncached bf16 y -> ysb ----------
    {
        const int b = tid >> 3, h0 = (tid & 7) * 16;
        const ull* src = (const ull*)(ycur + (bg * 64 + b) * 128 + h0);
        ull v0 = ld_agent_u64(src + 0);
        ull v1 = ld_agent_u64(src + 1);
        ull v2 = ld_agent_u64(src + 2);
        ull v3 = ld_agent_u64(src + 3);
        ull* dst = (ull*)&sm.ysb[b * 136 + h0];
        dst[0] = v0; dst[1] = v1; dst[2] = v2; dst[3] = v3;
    }
    __syncthreads();

    // ---------- phase 1: h1 = silu(W0 @ ys^T + b0), wave w -> ot {2w,2w+1} x 4 bq ----------
    {
        short8 af[2][4];
        #pragma unroll
        for (int oi = 0; oi < 2; ++oi)
            #pragma unroll
            for (int kc = 0; kc < 4; ++kc)
                af[oi][kc] = *reinterpret_cast<const short8*>(W0p + ((w * 2 + oi) * 4 + kc) * 512 + lane * 8);
        f32x4 acc[2][4];
        #pragma unroll
        for (int oi = 0; oi < 2; ++oi)
            #pragma unroll
            for (int bq = 0; bq < 4; ++bq) acc[oi][bq] = (f32x4){0.f, 0.f, 0.f, 0.f};
        #pragma unroll
        for (int kc = 0; kc < 4; ++kc) {
            short8 bfr[4];
            #pragma unroll
            for (int bq = 0; bq < 4; ++bq)
                bfr[bq] = *reinterpret_cast<const short8*>(&sm.ysb[(bq * 16 + rr) * 136 + kc * 32 + q * 8]);
            #pragma unroll
            for (int oi = 0; oi < 2; ++oi)
                #pragma unroll
                for (int bq = 0; bq < 4; ++bq)
                    acc[oi][bq] = __builtin_amdgcn_mfma_f32_16x16x32_bf16(af[oi][kc], bfr[bq], acc[oi][bq], 0, 0, 0);
        }
        #pragma unroll
        for (int oi = 0; oi < 2; ++oi) {
            const int ho = (w * 2 + oi) * 16 + q * 4;
            #pragma unroll
            for (int bq = 0; bq < 4; ++bq) {
                float vv[4];
                #pragma unroll
                for (int j = 0; j < 4; ++j)
                    vv[j] = fast_silu(acc[oi][bq][j] + sm.b0sh[ho + j]);
                ull pk = (ull)cvtpk(vv[0], vv[1]) | ((ull)cvtpk(vv[2], vv[3]) << 32);
                *reinterpret_cast<ull*>(&sm.h1b[(bq * 16 + rr) * 264 + ho]) = pk;
            }
        }
    }
    __syncthreads();

    // ---------- phase 2: h2 = silu(W1 @ h1^T + b1) ----------
    {
        short8 af[2][8];
        #pragma unroll
        for (int oi = 0; oi < 2; ++oi)
            #pragma unroll
            for (int kc = 0; kc < 8; ++kc)
                af[oi][kc] = *reinterpret_cast<const short8*>(W1p + ((w * 2 + oi) * 8 + kc) * 512 + lane * 8);
        f32x4 acc[2][4];
        #pragma unroll
        for (int oi = 0; oi < 2; ++oi)
            #pragma unroll
            for (int bq = 0; bq < 4; ++bq) acc[oi][bq] = (f32x4){0.f, 0.f, 0.f, 0.f};
        #pragma unroll
        for (int kc = 0; kc < 8; ++kc) {
            short8 bfr[4];
            #pragma unroll
            for (int bq = 0; bq < 4; ++bq)
                bfr[bq] = *reinterpret_cast<const short8*>(&sm.h1b[(bq * 16 + rr) * 264 + kc * 32 + q * 8]);
            #pragma unroll
            for (int oi = 0; oi < 2; ++oi)
                #pragma unroll
                for (int bq = 0; bq < 4; ++bq)
                    acc[oi][bq] = __builtin_amdgcn_mfma_f32_16x16x32_bf16(af[oi][kc], bfr[bq], acc[oi][bq], 0, 0, 0);
        }
        #pragma unroll
        for (int oi = 0; oi < 2; ++oi) {
            const int ho = (w * 2 + oi) * 16 + q * 4;
            #pragma unroll
            for (int bq = 0; bq < 4; ++bq) {
                float vv[4];
                #pragma unroll
                for (int j = 0; j < 4; ++j)
                    vv[j] = fast_silu(acc[oi][bq][j] + sm.b1sh[ho + j]);
                ull pk = (ull)cvtpk(vv[0], vv[1]) | ((ull)cvtpk(vv[2], vv[3]) << 32);
                *reinterpret_cast<ull*>(&sm.h2b[(bq * 16 + rr) * 264 + ho]) = pk;
            }
        }
    }
    __syncthreads();

    // ---------- phase 3: A-tile = 4h x 4lv of W2; wave w -> q4 {2w,2w+1} x 4 bq ----------
    {
        short8 af[2][8];
        #pragma unroll
        for (int t2 = 0; t2 < 2; ++t2)
            #pragma unroll
            for (int kc = 0; kc < 8; ++kc)
                af[t2][kc] = *reinterpret_cast<const short8*>(W2p + (size_t)(ht * 16 + w * 2 + t2) * 4096 + kc * 512 + lane * 8);
        f32x4 acc[2][4];
        #pragma unroll
        for (int t2 = 0; t2 < 2; ++t2)
            #pragma unroll
            for (int bq = 0; bq < 4; ++bq) acc[t2][bq] = (f32x4){0.f, 0.f, 0.f, 0.f};
        #pragma unroll
        for (int kc = 0; kc < 8; ++kc) {
            short8 bfr[4];
            #pragma unroll
            for (int bq = 0; bq < 4; ++bq)
                bfr[bq] = *reinterpret_cast<const short8*>(&sm.h2b[(bq * 16 + rr) * 264 + kc * 32 + q * 8]);
            #pragma unroll
            for (int t2 = 0; t2 < 2; ++t2)
                #pragma unroll
                for (int bq = 0; bq < 4; ++bq)
                    acc[t2][bq] = __builtin_amdgcn_mfma_f32_16x16x32_bf16(af[t2][kc], bfr[bq], acc[t2][bq], 0, 0, 0);
        }
        // per lane: batch col = bq*16 + rr, lv = q4*4 + q, h_local = j
        float kacc[4][4];
        #pragma unroll
        for (int bq = 0; bq < 4; ++bq)
            #pragma unroll
            for (int j = 0; j < 4; ++j) kacc[bq][j] = 0.f;
        #pragma unroll
        for (int t2 = 0; t2 < 2; ++t2) {
            const int lv = (w * 2 + t2) * 4 + q;
            #pragma unroll
            for (int bq = 0; bq < 4; ++bq) {
                float gv = sm.gsh[(bq * 16 + rr) * 65 + lv];
                #pragma unroll
                for (int j = 0; j < 4; ++j) {
                    float x = acc[t2][bq][j] + sm.b2sh[j * 64 + lv];
                    kacc[bq][j] += fast_tanh(x) * gv;
                }
            }
        }
        // reduce over lv-quarter groups (lane bits 4,5)
        #pragma unroll
        for (int bq = 0; bq < 4; ++bq)
            #pragma unroll
            for (int j = 0; j < 4; ++j) {
                float v = kacc[bq][j];
                v += __shfl_xor(v, 16);
                v += __shfl_xor(v, 32);
                kacc[bq][j] = v;
            }
        if (q == 0) {
            #pragma unroll
            for (int bq = 0; bq < 4; ++bq)
                #pragma unroll
                for (int j = 0; j < 4; ++j)
                    sm.kred[w][bq][j][rr] = kacc[bq][j];
        }
    }
    __syncthreads();

    // ---------- epilogue: 128 owner threads, each (b, 2 h) ----------
    if (tid < 128) {
        const int b = tid >> 1, hs = tid & 1;
        float s0 = 0.f, s1 = 0.f;
        #pragma unroll
        for (int ww = 0; ww < 8; ++ww) {
            s0 += sm.kred[ww][b >> 4][hs * 2 + 0][b & 15];
            s1 += sm.kred[ww][b >> 4][hs * 2 + 1][b & 15];
        }
        float nv0, nv1;
        if constexpr (STAGE == 1) {
            kr[0][0] = s0; kr[1][0] = s1;
            nv0 = yreg[0] + DT * (cA2[0] * s0);
            nv1 = yreg[1] + DT * (cA2[0] * s1);
        } else if constexpr (STAGE == 2) {
            kr[0][1] = s0; kr[1][1] = s1;
            nv0 = yreg[0] + DT * (cA3[0] * kr[0][0] + cA3[1] * s0);
            nv1 = yreg[1] + DT * (cA3[0] * kr[1][0] + cA3[1] * s1);
        } else if constexpr (STAGE == 3) {
            kr[0][2] = s0; kr[1][2] = s1;
            nv0 = yreg[0] + DT * (cA4[0] * kr[0][0] + cA4[1] * kr[0][1] + cA4[2] * s0);
            nv1 = yreg[1] + DT * (cA4[0] * kr[1][0] + cA4[1] * kr[1][1] + cA4[2] * s1);
        } else if constexpr (STAGE == 4) {
            kr[0][3] = s0; kr[1][3] = s1;
            nv0 = yreg[0] + DT * (cA5[0] * kr[0][0] + cA5[1] * kr[0][1] + cA5[2] * kr[0][2] + cA5[3] * s0);
            nv1 = yreg[1] + DT * (cA5[0] * kr[1][0] + cA5[1] * kr[1][1] + cA5[2] * kr[1][2] + cA5[3] * s1);
        } else if constexpr (STAGE == 5) {
            kr[0][4] = s0; kr[1][4] = s1;
            nv0 = yreg[0] + DT * (cA6[0] * kr[0][0] + cA6[1] * kr[0][1] + cA6[2] * kr[0][2] + cA6[3] * kr[0][3] + cA6[4] * s0);
            nv1 = yreg[1] + DT * (cA6[0] * kr[1][0] + cA6[1] * kr[1][1] + cA6[2] * kr[1][2] + cA6[3] * kr[1][3] + cA6[4] * s1);
        } else {
            nv0 = yreg[0] + DT * (0.09646076681806523f * kr[0][0] + 0.01f * kr[0][1]
                 + 0.4798896504144996f * kr[0][2] + 1.379008574103742f * kr[0][3]
                 + (-3.290069515436081f) * kr[0][4] + 2.324710524099774f * s0);
            nv1 = yreg[1] + DT * (0.09646076681806523f * kr[1][0] + 0.01f * kr[1][1]
                 + 0.4798896504144996f * kr[1][2] + 1.379008574103742f * kr[1][3]
                 + (-3.290069515436081f) * kr[1][4] + 2.324710524099774f * s1);
            yreg[0] = nv0; yreg[1] = nv1;
        }
        const int gi = (bg * 64 + b) * 128 + ht * 4 + hs * 2;
        st_agent_u32(reinterpret_cast<unsigned*>(ynxt + gi), cvtpk(nv0, nv1));
        if constexpr (STAGE == 6) {
            if (s == NSTEPS - 1) {
                st_agent_f(&yfinal[gi], nv0);
                st_agent_f(&yfinal[gi + 1], nv1);
            }
        }
    }

    // ---------- flag (syncthreads drains vmcnt -> stores visible before add) ----------
    __syncthreads();
    if (tid == 0)
        __hip_atomic_fetch_add(&barctr[bg * 16], 1u, __ATOMIC_RELAXED, __HIP_MEMORY_SCOPE_AGENT);
}

__global__ __launch_bounds__(512, 2) void rde_persistent(
    float* y0f, unsigned short* ybf, float* yfinal, unsigned* barctr,
    const short* W0p, const short* W1p, const short* W2p,
    const float* b0, const float* b1, const float* b2,
    const float* logsig)
{
    __shared__ Smem sm;
    const int tid = threadIdx.x;
    const int bg  = blockIdx.x >> 5;    // 0..7  (64 batch rows)
    const int ht  = blockIdx.x & 31;    // 0..31 (4 h) ; ht&7 == XCD
    // ---- one-time LDS init ----
    if (tid < 256) {
        sm.b0sh[tid] = b0[tid];
        int hl = tid >> 6, lv = tid & 63;
        sm.b2sh[tid] = (lv < 63) ? b2[(ht * 4 + hl) * 63 + lv] : 0.f;
    } else {
        sm.b1sh[tid - 256] = b1[tid - 256];
    }
    {
        const int b = tid >> 3, l0 = (tid & 7) * 8;
        const float* gp = logsig + (bg * 64 + b) * 16384 + 1;   // idx 0
        #pragma unroll
        for (int ii = 0; ii < 8; ++ii) {
            int l = l0 + ii;
            sm.gsh[b * 65 + l] = (l < 63) ? gp[l] : 0.f;
        }
    }
    float yreg[2] = {0.f, 0.f};
    float kr[2][5] = {{0.f,0.f,0.f,0.f,0.f},{0.f,0.f,0.f,0.f,0.f}};
    if (tid < 128) {
        const int b = tid >> 1, hs = tid & 1;
        const int gi = (bg * 64 + b) * 128 + ht * 4 + hs * 2;
        yreg[0] = y0f[gi];
        yreg[1] = y0f[gi + 1];
    }
    // (first syncthreads inside do_stage<1> covers init)
    #pragma unroll 1
    for (int s = 0; s < NSTEPS; ++s) {
        const int g6 = s * 6;
        do_stage<1>(sm, s, g6 + 0, bg, ht, tid, ybf, yfinal, W0p, W1p, W2p, logsig, barctr, yreg, kr);
        do_stage<2>(sm, s, g6 + 1, bg, ht, tid, ybf, yfinal, W0p, W1p, W2p, logsig, barctr, yreg, kr);
        do_stage<3>(sm, s, g6 + 2, bg, ht, tid, ybf, yfinal, W0p, W1p, W2p, logsig, barctr, yreg, kr);
        do_stage<4>(sm, s, g6 + 3, bg, ht, tid, ybf, yfinal, W0p, W1p, W2p, logsig, barctr, yreg, kr);
        do_stage<5>(sm, s, g6 + 4, bg, ht, tid, ybf, yfinal, W0p, W1p, W2p, logsig, barctr, yreg, kr);
        do_stage<6>(sm, s, g6 + 5, bg, ht, tid, ybf, yfinal, W0p, W1p, W2p, logsig, barctr, yreg, kr);
    }
}

// ---------------- final: softmax(yf @ l2w^T + l2b) ----------------
__global__ void out_kernel(const float* __restrict__ yf, const float* __restrict__ l2w,
                           const float* __restrict__ l2b, float* __restrict__ out) {
    int b = blockIdx.x, t = threadIdx.x;   // 64 threads
    float ya = yf[b * 128 + t], yb = yf[b * 128 + 64 + t];
    __shared__ float lg[10];
    for (int c = 0; c < 10; ++c) {
        float p = ya * l2w[c * 128 + t] + yb * l2w[c * 128 + 64 + t];
        for (int off = 32; off > 0; off >>= 1) p += __shfl_down(p, off);
        if (t == 0) lg[c] = p + l2b[c];
    }
    __syncthreads();
    if (t == 0) {
        float m = lg[0];
        for (int c = 1; c < 10; ++c) m = fmaxf(m, lg[c]);
        float s = 0.f, e[10];
        for (int c = 0; c < 10; ++c) { e[c] = expf(lg[c] - m); s += e[c]; }
        for (int c = 0; c < 10; ++c) out[b * 10 + c] = e[c] / s;
    }
}

extern "C" void kernel_launch(void* const* d_in, const int* in_sizes, int n_in,
                              void* d_out, int out_size, void* d_ws, size_t ws_size,
                              hipStream_t stream) {
    const float* logsig = (const float*)d_in[2];
    const float* x0  = (const float*)d_in[3];
    const float* W0  = (const float*)d_in[4];
    const float* b0  = (const float*)d_in[5];
    const float* W1  = (const float*)d_in[6];
    const float* b1  = (const float*)d_in[7];
    const float* W2  = (const float*)d_in[8];
    const float* b2  = (const float*)d_in[9];
    const float* l1w = (const float*)d_in[10];
    const float* l1b = (const float*)d_in[11];
    const float* l2w = (const float*)d_in[12];
    const float* l2b = (const float*)d_in[13];
    float* out = (float*)d_out;

    char* ws = (char*)d_ws;
    float*          y0f    = (float*)(ws);                  // 256 KB f32
    unsigned short* ybf    = (unsigned short*)(ws + 262144);// 2 x 128 KB bf16
    float*          yfinal = (float*)(ws + 524288);         // 256 KB f32
    short*          W0p    = (short*)(ws + 786432);         // 64 KB
    short*          W1p    = (short*)(ws + 851968);         // 128 KB
    short*          W2p    = (short*)(ws + 983040);         // 4 MB
    unsigned*       barctr = (unsigned*)(ws + 5177344);     // 8 bg x 16 uints

    hipMemsetAsync(barctr, 0, 32 * 16 * sizeof(unsigned), stream);
    perm_w0<<<128, 256, 0, stream>>>(W0, W0p);
    perm_w1<<<256, 256, 0, stream>>>(W1, W1p);
    perm_w2<<<8192, 256, 0, stream>>>(W2, W2p);
    y0_kernel<<<256, 256, 0, stream>>>(x0, l1w, l1b, y0f, ybf);

    void* args[] = {&y0f, &ybf, &yfinal, &barctr, &W0p, &W1p, &W2p, &b0, &b1, &b2, &logsig};
    hipLaunchCooperativeKernel((const void*)rde_persistent, dim3(256), dim3(512), args, 0, stream);

    out_kernel<<<512, 64, 0, stream>>>(yfinal, l2w, l2b, out);
}